// Round 1
// baseline (8466.702 us; speedup 1.0000x reference)
//
#include <hip/hip_runtime.h>
#include <cstdint>

typedef unsigned short u16;
typedef __attribute__((ext_vector_type(8))) short short8;
typedef __attribute__((ext_vector_type(4))) float f32x4;

#define B_ 16
#define P_ 128
#define T_ 16384
#define F_ 64
#define H_ 256
#define O_ 32
#define MBLK 16
#define NBLOCKS 128
#define NTHREADS 512

// workspace layout (bytes)
#define WS_STARTS 0         // 2048 * int32
#define WS_WIH0   8192      // 64 tiles * KF2 * 512 bf16 = 131072 B
#define WS_WHH0   139264    // 64 * 8 * 512 * 2 = 524288 B
#define WS_WIH1   663552
#define WS_WHH1   1187840
#define WS_WFC    1712128   // 2 * 8 * 512 * 2 = 16384 B
#define WS_B0     1728512   // 1024 fp32
#define WS_B1     1732608

#define HOFF 8388608LL              // out_final floats
#define COFF 9437184LL              // HOFF + 2*2048*256

__device__ __forceinline__ u16 f2bf(float f) {
  uint32_t u = __float_as_uint(f);
  u += 0x7FFFu + ((u >> 16) & 1u);
  return (u16)(u >> 16);
}
__device__ __forceinline__ float sigm(float x) { return 1.f / (1.f + __expf(-x)); }
__device__ __forceinline__ float tanhf_(float x) {
  float e = __expf(-2.f * fabsf(x));
  float t = (1.f - e) / (1.f + e);
  return x < 0.f ? -t : t;
}

// per-batch exclusive prefix sum of path lengths
__global__ void k_starts(const int* __restrict__ lpp, int* __restrict__ starts) {
  int b = threadIdx.x;
  if (b >= B_) return;
  int run = 0;
  for (int p = 0; p < P_; p++) { starts[b * P_ + p] = run; run += lpp[b * P_ + p]; }
}

// pack weight matrix into fragment-major bf16 layout:
// flat idx = ((tile*KF + kf)*512 + lane*8 + i)
// element = W[row][k], k = kf*32 + (lane>>4)*8 + i
// perm=1: tile = wave*8 + nt; row = (nt&3)*256 + wave*32 + ((nt>>2)<<4) + (lane&15)
// perm=0: row = tile*16 + (lane&15)
__global__ void k_pack(const float* __restrict__ W, u16* __restrict__ o,
                       int ntiles, int KF, int K, int perm) {
  int idx = blockIdx.x * 256 + threadIdx.x;
  if (idx >= ntiles * KF * 512) return;
  int i = idx & 7;
  int lane = (idx >> 3) & 63;
  int rem = idx >> 9;
  int kf = rem % KF, tile = rem / KF;
  int c = lane & 15, kg = lane >> 4;
  int row;
  if (perm) { int wv = tile >> 3, nt = tile & 7; row = (nt & 3) * 256 + wv * 32 + ((nt >> 2) << 4) + c; }
  else row = tile * 16 + c;
  int k = kf * 32 + kg * 8 + i;
  o[idx] = f2bf(W[(long long)row * K + k]);
}

__global__ void k_bias(const float* bih0, const float* bhh0,
                       const float* bih1, const float* bhh1,
                       float* b0, float* b1) {
  int n = blockIdx.x * 256 + threadIdx.x;
  if (n >= 1024) return;
  int wv = n >> 7, r = n & 127, nt = r >> 4, c = n & 15;
  int row = (nt & 3) * 256 + wv * 32 + ((nt >> 2) << 4) + c;
  b0[n] = bih0[row] + bhh0[row];
  b1[n] = bih1[row] + bhh1[row];
}

__launch_bounds__(NTHREADS, 1)
__global__ void lstm_main(const float* __restrict__ x,
                          const int* __restrict__ lpp,
                          const float* __restrict__ bfc,
                          const uint8_t* __restrict__ ws,
                          float* __restrict__ out) {
  const int g = blockIdx.x;
  const int tid = threadIdx.x;
  const int w = tid >> 6;        // wave 0..7, owns permuted gate cols [w*128, w*128+128)
  const int lane = tid & 63;
  const int lr = lane & 15;      // A-row / B-col within tile
  const int lg = lane >> 4;      // k-group; D rows lg*4..lg*4+3

  __shared__ __align__(16) u16 x_lds[16][72];          // pad 8 to stagger banks
  __shared__ __align__(16) u16 h0_lds[2][16][264];
  __shared__ __align__(16) u16 h1_lds[2][16][264];
  __shared__ __align__(16) u16 y0_lds[16][264];
  __shared__ __align__(16) u16 y1_lds[16][264];
  __shared__ int len_s[16];
  __shared__ int start_s[16];
  __shared__ int bb_s[16];

  const int* starts = (const int*)(ws + WS_STARTS);
  if (tid < 16) {
    int sg = g * MBLK + tid;
    len_s[tid] = lpp[sg];
    start_s[tid] = starts[sg];
    bb_s[tid] = sg >> 7;   // P_=128 paths per batch
  }
  for (int i = tid; i < 16 * 264; i += NTHREADS) {
    ((u16*)h0_lds)[i] = 0;   // zero buffer 0 of each
    ((u16*)h1_lds)[i] = 0;
  }
  __syncthreads();

  int maxlen = 0;
  #pragma unroll
  for (int i = 0; i < 16; i++) maxlen = max(maxlen, len_s[i]);

  // per-lane row info (D rows = seqs lg*4+v)
  int len_r[4];
  long long obase[4];
  #pragma unroll
  for (int v = 0; v < 4; v++) {
    int r = lg * 4 + v;
    len_r[v] = len_s[r];
    obase[v] = ((long long)bb_s[r] * T_ + start_s[r]) * O_ + (w & 1) * 16 + lr;
  }

  // x staging assignment: thread -> (seq, 2 floats)
  const int sseq = tid >> 5;
  const int sk2 = (tid & 31) << 1;
  const int slen = len_s[sseq];
  const float* xptr = x + ((long long)bb_s[sseq] * T_ + start_s[sseq]) * F_ + sk2;
  uint32_t* xdst = (uint32_t*)&x_lds[sseq][sk2];

  const float* b0p = (const float*)(ws + WS_B0);
  const float* b1p = (const float*)(ws + WS_B1);
  float b0r[8], b1r[8];
  #pragma unroll
  for (int nt = 0; nt < 8; nt++) {
    b0r[nt] = b0p[w * 128 + nt * 16 + lr];
    b1r[nt] = b1p[w * 128 + nt * 16 + lr];
  }
  const u16* wih0 = (const u16*)(ws + WS_WIH0) + (w * 8) * 2 * 512 + lane * 8;
  const u16* whh0 = (const u16*)(ws + WS_WHH0) + (w * 8) * 8 * 512 + lane * 8;
  const u16* wih1 = (const u16*)(ws + WS_WIH1) + (w * 8) * 8 * 512 + lane * 8;
  const u16* whh1 = (const u16*)(ws + WS_WHH1) + (w * 8) * 8 * 512 + lane * 8;
  const u16* wfc  = (const u16*)(ws + WS_WFC) + lane * 8;
  float bfc_r = (w < 2) ? bfc[w * 16 + lr] : 0.f;

  float h0r[8], c0r[8], h1r[8], c1r[8];   // [h2*4 + v]
  #pragma unroll
  for (int i = 0; i < 8; i++) { h0r[i] = 0.f; c0r[i] = 0.f; h1r[i] = 0.f; c1r[i] = 0.f; }

  for (int t = 0; t < maxlen; t++) {
    // ---- stage x_t (bf16) ----
    {
      float xa = 0.f, xb = 0.f;
      if (t < slen) {
        float2 xv = *(const float2*)(xptr + (long long)t * F_);
        xa = xv.x; xb = xv.y;
      }
      *xdst = (uint32_t)f2bf(xa) | ((uint32_t)f2bf(xb) << 16);
    }
    __syncthreads();
    const int cur = t & 1, nxt = cur ^ 1;

    // ---- layer 0: gates = x@Wih0^T + h0@Whh0^T + bias ----
    {
      short8 ax0 = *(const short8*)&x_lds[lr][lg * 8];
      short8 ax1 = *(const short8*)&x_lds[lr][32 + lg * 8];
      short8 ah[8];
      #pragma unroll
      for (int kf = 0; kf < 8; kf++)
        ah[kf] = *(const short8*)&h0_lds[cur][lr][kf * 32 + lg * 8];
      f32x4 acc[8];
      #pragma unroll
      for (int nt = 0; nt < 8; nt++) {
        f32x4 a = {0.f, 0.f, 0.f, 0.f};
        a = __builtin_amdgcn_mfma_f32_16x16x32_bf16(ax0, *(const short8*)(wih0 + ((nt * 2 + 0) << 9)), a, 0, 0, 0);
        a = __builtin_amdgcn_mfma_f32_16x16x32_bf16(ax1, *(const short8*)(wih0 + ((nt * 2 + 1) << 9)), a, 0, 0, 0);
        #pragma unroll
        for (int kf = 0; kf < 8; kf++)
          a = __builtin_amdgcn_mfma_f32_16x16x32_bf16(ah[kf], *(const short8*)(whh0 + ((nt * 8 + kf) << 9)), a, 0, 0, 0);
        acc[nt] = a;
      }
      #pragma unroll
      for (int h2 = 0; h2 < 2; h2++) {
        #pragma unroll
        for (int v = 0; v < 4; v++) {
          float gi = acc[h2 * 4 + 0][v] + b0r[h2 * 4 + 0];
          float gf = acc[h2 * 4 + 1][v] + b0r[h2 * 4 + 1];
          float gg = acc[h2 * 4 + 2][v] + b0r[h2 * 4 + 2];
          float go = acc[h2 * 4 + 3][v] + b0r[h2 * 4 + 3];
          float ii = sigm(gi), ff = sigm(gf), gv = tanhf_(gg), oo = sigm(go);
          float cn = ff * c0r[h2 * 4 + v] + ii * gv;
          float hn = oo * tanhf_(cn);
          bool m = (t < len_r[v]);
          if (m) { c0r[h2 * 4 + v] = cn; h0r[h2 * 4 + v] = hn; }
          u16 hb = f2bf(h0r[h2 * 4 + v]);
          int r = lg * 4 + v, col = w * 32 + h2 * 16 + lr;
          h0_lds[nxt][r][col] = hb;
          y0_lds[r][col] = m ? hb : (u16)0;
        }
      }
    }
    __syncthreads();

    // ---- layer 1: gates = y0@Wih1^T + h1@Whh1^T + bias ----
    {
      short8 ay[8], ah[8];
      #pragma unroll
      for (int kf = 0; kf < 8; kf++) {
        ay[kf] = *(const short8*)&y0_lds[lr][kf * 32 + lg * 8];
        ah[kf] = *(const short8*)&h1_lds[cur][lr][kf * 32 + lg * 8];
      }
      f32x4 acc[8];
      #pragma unroll
      for (int nt = 0; nt < 8; nt++) {
        f32x4 a = {0.f, 0.f, 0.f, 0.f};
        #pragma unroll
        for (int kf = 0; kf < 8; kf++)
          a = __builtin_amdgcn_mfma_f32_16x16x32_bf16(ay[kf], *(const short8*)(wih1 + ((nt * 8 + kf) << 9)), a, 0, 0, 0);
        #pragma unroll
        for (int kf = 0; kf < 8; kf++)
          a = __builtin_amdgcn_mfma_f32_16x16x32_bf16(ah[kf], *(const short8*)(whh1 + ((nt * 8 + kf) << 9)), a, 0, 0, 0);
        acc[nt] = a;
      }
      #pragma unroll
      for (int h2 = 0; h2 < 2; h2++) {
        #pragma unroll
        for (int v = 0; v < 4; v++) {
          float gi = acc[h2 * 4 + 0][v] + b1r[h2 * 4 + 0];
          float gf = acc[h2 * 4 + 1][v] + b1r[h2 * 4 + 1];
          float gg = acc[h2 * 4 + 2][v] + b1r[h2 * 4 + 2];
          float go = acc[h2 * 4 + 3][v] + b1r[h2 * 4 + 3];
          float ii = sigm(gi), ff = sigm(gf), gv = tanhf_(gg), oo = sigm(go);
          float cn = ff * c1r[h2 * 4 + v] + ii * gv;
          float hn = oo * tanhf_(cn);
          bool m = (t < len_r[v]);
          if (m) { c1r[h2 * 4 + v] = cn; h1r[h2 * 4 + v] = hn; }
          u16 hb = f2bf(h1r[h2 * 4 + v]);
          int r = lg * 4 + v, col = w * 32 + h2 * 16 + lr;
          h1_lds[nxt][r][col] = hb;
          y1_lds[r][col] = m ? hb : (u16)0;
        }
      }
    }
    __syncthreads();

    // ---- FC: out = y1 @ Wfc^T + bfc (waves 0,1 only) ----
    if (w < 2) {
      f32x4 a = {0.f, 0.f, 0.f, 0.f};
      #pragma unroll
      for (int kf = 0; kf < 8; kf++) {
        short8 ayv = *(const short8*)&y1_lds[lr][kf * 32 + lg * 8];
        a = __builtin_amdgcn_mfma_f32_16x16x32_bf16(ayv, *(const short8*)(wfc + ((w * 8 + kf) << 9)), a, 0, 0, 0);
      }
      #pragma unroll
      for (int v = 0; v < 4; v++)
        if (t < len_r[v]) out[obase[v] + (long long)t * O_] = a[v] + bfc_r;
    }
  }

  // ---- final states: h_t (2,2048,256), c_t (2,2048,256) ----
  #pragma unroll
  for (int h2 = 0; h2 < 2; h2++) {
    #pragma unroll
    for (int v = 0; v < 4; v++) {
      int r = lg * 4 + v;
      long long sg = (long long)g * MBLK + r;
      int j = w * 32 + h2 * 16 + lr;
      out[HOFF + sg * H_ + j]          = h0r[h2 * 4 + v];
      out[HOFF + 524288 + sg * H_ + j] = h1r[h2 * 4 + v];
      out[COFF + sg * H_ + j]          = c0r[h2 * 4 + v];
      out[COFF + 524288 + sg * H_ + j] = c1r[h2 * 4 + v];
    }
  }
}

extern "C" void kernel_launch(void* const* d_in, const int* in_sizes, int n_in,
                              void* d_out, int out_size, void* d_ws, size_t ws_size,
                              hipStream_t stream) {
  const float* x    = (const float*)d_in[0];
  const int*   lpp  = (const int*)d_in[2];
  const float* Wih0 = (const float*)d_in[4];
  const float* Whh0 = (const float*)d_in[5];
  const float* bih0 = (const float*)d_in[6];
  const float* bhh0 = (const float*)d_in[7];
  const float* Wih1 = (const float*)d_in[8];
  const float* Whh1 = (const float*)d_in[9];
  const float* bih1 = (const float*)d_in[10];
  const float* bhh1 = (const float*)d_in[11];
  const float* Wfc  = (const float*)d_in[12];
  const float* bfc  = (const float*)d_in[13];
  uint8_t* ws = (uint8_t*)d_ws;
  float* out = (float*)d_out;

  // zero the scatter target region (rest of out is fully overwritten)
  hipMemsetAsync(d_out, 0, 8388608ull * 4, stream);

  k_starts<<<1, 16, 0, stream>>>(lpp, (int*)(ws + WS_STARTS));
  k_pack<<<256, 256, 0, stream>>>(Wih0, (u16*)(ws + WS_WIH0), 64, 2, 64, 1);
  k_pack<<<1024, 256, 0, stream>>>(Whh0, (u16*)(ws + WS_WHH0), 64, 8, 256, 1);
  k_pack<<<1024, 256, 0, stream>>>(Wih1, (u16*)(ws + WS_WIH1), 64, 8, 256, 1);
  k_pack<<<1024, 256, 0, stream>>>(Whh1, (u16*)(ws + WS_WHH1), 64, 8, 256, 1);
  k_pack<<<32, 256, 0, stream>>>(Wfc, (u16*)(ws + WS_WFC), 2, 8, 256, 0);
  k_bias<<<4, 256, 0, stream>>>(bih0, bhh0, bih1, bhh1,
                                (float*)(ws + WS_B0), (float*)(ws + WS_B1));
  lstm_main<<<NBLOCKS, NTHREADS, 0, stream>>>(x, lpp, bfc, ws, out);
}